// Round 8
// baseline (274.796 us; speedup 1.0000x reference)
//
#include <hip/hip_runtime.h>
#include <hip/hip_bf16.h>

// ---------------------------------------------------------------------------
// EncoderBlock round 8:
//  - gemm64: 128(M)x64(N) tile, BK=32, double-buffered 24KB LDS ->
//    grids qkv 768 (3/CU), fc1 1024 (4/CU), oproj/fc2 512 (2/CU).
//    (round 7: 64KB dbuf capped 2 blocks/CU, only -3us; m132 trap)
//    Swizzle for 64B rows: chunk c of row m at pos = c ^ ((m>>1)&3)
//    -> ds_read_b128 2-way bank (free), gl_lds dest lane-contiguous.
//  - attn: row-sum via ones-MFMA (P @ 1) -> deletes 16 sum-shuffles/tile
//    + final l reduce; C/D layout replicates row sum into every lane.
// MFMA layouts (verified): A[m=lane&15][k=(lane>>4)*8+j],
//   B[k=(lane>>4)*8+j][n=lane&15], C/D row=(lane>>4)*4+reg, col=lane&15.
// ---------------------------------------------------------------------------

typedef __bf16 bf16;
typedef __attribute__((ext_vector_type(8))) __bf16 bf16x8;
typedef __attribute__((ext_vector_type(4))) __bf16 bf16x4;
typedef __attribute__((ext_vector_type(4))) float f32x4;

#define NTOK 2048
#define DM   1024
#define DFC  4096
#define QKVN 3072

__device__ inline void gl_lds16(const void* g, void* l) {
    __builtin_amdgcn_global_load_lds((const __attribute__((address_space(1))) void*)g,
                                     (__attribute__((address_space(3))) void*)l, 16, 0, 0);
}

// ---------------- LayerNorm row helper (torch: std ddof=1, /(std+eps)) -----
__device__ inline void ln_row(float4 v, const float* alpha, const float* beta,
                              bf16* outrow, int t) {
    float s  = v.x + v.y + v.z + v.w;
    float ss = v.x * v.x + v.y * v.y + v.z * v.z + v.w * v.w;
    __shared__ float red[8];
    int lane = t & 63, wv = t >> 6;
    #pragma unroll
    for (int o = 32; o > 0; o >>= 1) {
        s  += __shfl_down(s, o);
        ss += __shfl_down(ss, o);
    }
    if (lane == 0) { red[wv] = s; red[4 + wv] = ss; }
    __syncthreads();
    float S  = red[0] + red[1] + red[2] + red[3];
    float SS = red[4] + red[5] + red[6] + red[7];
    float mean = S * (1.0f / 1024.0f);
    float var  = (SS - S * mean) * (1.0f / 1023.0f);
    var = var < 0.f ? 0.f : var;
    float inv = 1.0f / (sqrtf(var) + 1e-6f);
    float4 a4 = reinterpret_cast<const float4*>(alpha)[t];
    float4 b4 = reinterpret_cast<const float4*>(beta)[t];
    bf16x4 o4;
    o4[0] = (bf16)(a4.x * (v.x - mean) * inv + b4.x);
    o4[1] = (bf16)(a4.y * (v.y - mean) * inv + b4.y);
    o4[2] = (bf16)(a4.z * (v.z - mean) * inv + b4.z);
    o4[3] = (bf16)(a4.w * (v.w - mean) * inv + b4.w);
    reinterpret_cast<bf16x4*>(outrow)[t] = o4;
}

// ---------------- prep: all weights fp32->bf16 AND ln1, one dispatch --------
__global__ __launch_bounds__(256) void prep_kernel(
    const float4* __restrict__ wq, const float4* __restrict__ wk,
    const float4* __restrict__ wv, const float4* __restrict__ wo,
    const float4* __restrict__ f1, const float4* __restrict__ f2,
    bf16x4* __restrict__ oqkv, bf16x4* __restrict__ oo,
    bf16x4* __restrict__ of1, bf16x4* __restrict__ of2,
    const float* __restrict__ x, const float* __restrict__ alpha1,
    const float* __restrict__ beta1, bf16* __restrict__ xn) {
    int blk = blockIdx.x;
    int t = threadIdx.x;
    if (blk < 12288) {
        int i = blk * 256 + t;
        const int Q = 262144;                        // 1024*1024/4
        float4 v;
        bf16x4* dst;
        if (i < 3 * Q) {
            v = (i < Q) ? wq[i] : (i < 2 * Q) ? wk[i - Q] : wv[i - 2 * Q];
            dst = oqkv + i;
        } else if (i < 4 * Q) {
            v = wo[i - 3 * Q];
            dst = oo + (i - 3 * Q);
        } else if (i < 8 * Q) {
            v = f1[i - 4 * Q];
            dst = of1 + (i - 4 * Q);
        } else {
            v = f2[i - 8 * Q];
            dst = of2 + (i - 8 * Q);
        }
        bf16x4 o;
        o[0] = (bf16)v.x; o[1] = (bf16)v.y; o[2] = (bf16)v.z; o[3] = (bf16)v.w;
        *dst = o;
    } else {
        int row = blk - 12288;
        float4 v = reinterpret_cast<const float4*>(x + (size_t)row * DM)[t];
        ln_row(v, alpha1, beta1, xn + (size_t)row * DM, t);
    }
}

// ---- o-proj split-K reduce + residual -> x2, fused ln2 -> xn (block=row) ---
__global__ __launch_bounds__(256) void reduce_ln_kernel(const float* __restrict__ p,
                                                        const float* __restrict__ resid,
                                                        const float* __restrict__ alpha,
                                                        const float* __restrict__ beta,
                                                        float* __restrict__ x2,
                                                        bf16* __restrict__ xn) {
    int row = blockIdx.x, t = threadIdx.x;
    size_t i4 = (size_t)row * 256 + t;
    float4 a = reinterpret_cast<const float4*>(p)[i4];
    float4 b = reinterpret_cast<const float4*>(p)[i4 + 524288];
    float4 r = reinterpret_cast<const float4*>(resid)[i4];
    float4 v;
    v.x = a.x + b.x + r.x; v.y = a.y + b.y + r.y;
    v.z = a.z + b.z + r.z; v.w = a.w + b.w + r.w;
    reinterpret_cast<float4*>(x2)[i4] = v;
    ln_row(v, alpha, beta, xn + (size_t)row * DM, t);
}

// ---- fc2 split-K reduce + bias + residual -> d_out (fp32) ------------------
__global__ __launch_bounds__(256) void reduce_out_kernel(const float* __restrict__ p,
                                                         const float* __restrict__ bias,
                                                         const float* __restrict__ x2,
                                                         float* __restrict__ out) {
    size_t i4 = (size_t)blockIdx.x * 256 + threadIdx.x;
    float4 a = reinterpret_cast<const float4*>(p)[i4];
    float4 b = reinterpret_cast<const float4*>(p)[i4 + 524288];
    float4 r = reinterpret_cast<const float4*>(x2)[i4];
    float4 bi = reinterpret_cast<const float4*>(bias)[i4 & 255];
    float4 o;
    o.x = a.x + b.x + r.x + bi.x; o.y = a.y + b.y + r.y + bi.y;
    o.z = a.z + b.z + r.z + bi.z; o.w = a.w + b.w + r.w + bi.w;
    reinterpret_cast<float4*>(out)[i4] = o;
}

// ---------------- GEMM: 128x64 tile, BK=32, dbuf 24KB, swizzled LDS ---------
// 4 waves in 2(M)x2(N): wave tile 64(M) x 32(N). 8 MFMA/wave/iter.
// LDS: chunk c (8 bf16) of row m at pos = c ^ ((m>>1)&3); rows are 64 B.
// Bank check (read): lane r base bank (r*16)%32; pos = q^((r>>1)&3) distinct
// across r=0,2,4,6 -> every (bank,pos) pair hit exactly twice = 2-way (free).
// Staging: A slot s=(w+j*4)*64+lane (j=0,1), B slot s=w*64+lane;
// row=s>>2, pos=lane&3, csrc=(lane&3)^((lane>>3)&3).
// EPI: 0 = store bf16; 1 = relu(v+bias) bf16; 4 = fp32 partial at z*M*N
template <int EPI>
__global__ __launch_bounds__(256) void gemm64(const bf16* __restrict__ A,
                                              const bf16* __restrict__ Bt,
                                              void* __restrict__ outp,
                                              const float* __restrict__ bias,
                                              int M, int N, int K, int kslice) {
    __shared__ bf16 As[2][128 * 32];   // 16 KB
    __shared__ bf16 Bs[2][64 * 32];    // 8 KB
    int tid = threadIdx.x;
    int lane = tid & 63, w = tid >> 6;
    int q = lane >> 4, r = lane & 15;
    int wm = w >> 1, wn = w & 1;
    int m0 = blockIdx.y * 128, n0 = blockIdx.x * 64;
    int kbeg = blockIdx.z * kslice;
    int nit = kslice / 32;
    f32x4 acc[4][2] = {};

    int csrc = (lane & 3) ^ ((lane >> 3) & 3);
    int srow = w * 16 + (lane >> 2);
    const bf16* agp0 = A  + (size_t)(m0 + srow) * K + kbeg + csrc * 8;
    const bf16* agp1 = A  + (size_t)(m0 + 64 + srow) * K + kbeg + csrc * 8;
    const bf16* bgp  = Bt + (size_t)(n0 + srow) * K + kbeg + csrc * 8;

    int pos = (q ^ ((r >> 1) & 3)) * 8;
    int aoff = (wm * 64 + r) * 32 + pos;
    int boff = (wn * 32 + r) * 32 + pos;

    auto stage = [&](int it, int b) {
        int k0 = it * 32;
        gl_lds16(agp0 + k0, &As[b][w * 512 + lane * 8]);
        gl_lds16(agp1 + k0, &As[b][(w + 4) * 512 + lane * 8]);
        gl_lds16(bgp  + k0, &Bs[b][w * 512 + lane * 8]);
    };

    stage(0, 0);
    for (int it = 0; it < nit; ++it) {
        __syncthreads();                       // buf[it&1] ready (vmcnt drain)
        if (it + 1 < nit) stage(it + 1, (it + 1) & 1);
        const bf16* Ab = &As[it & 1][aoff];
        const bf16* Bb = &Bs[it & 1][boff];
        bf16x8 af[4], bfv[2];
        #pragma unroll
        for (int t = 0; t < 4; ++t)
            af[t] = *reinterpret_cast<const bf16x8*>(Ab + t * 512);
        #pragma unroll
        for (int u = 0; u < 2; ++u)
            bfv[u] = *reinterpret_cast<const bf16x8*>(Bb + u * 512);
        #pragma unroll
        for (int t = 0; t < 4; ++t)
            #pragma unroll
            for (int u = 0; u < 2; ++u)
                acc[t][u] = __builtin_amdgcn_mfma_f32_16x16x32_bf16(af[t], bfv[u], acc[t][u], 0, 0, 0);
    }

    size_t zoff = (size_t)blockIdx.z * M * N;
    #pragma unroll
    for (int t = 0; t < 4; ++t) {
        #pragma unroll
        for (int u = 0; u < 2; ++u) {
            #pragma unroll
            for (int i = 0; i < 4; ++i) {
                int mm = m0 + wm * 64 + t * 16 + q * 4 + i;
                int nn = n0 + wn * 32 + u * 16 + r;
                size_t idx = (size_t)mm * N + nn;
                float v = acc[t][u][i];
                if (EPI == 0) {
                    ((bf16*)outp)[idx] = (bf16)v;
                } else if (EPI == 1) {
                    v += bias[nn];
                    ((bf16*)outp)[idx] = (bf16)(v > 0.f ? v : 0.f);
                } else {
                    ((float*)outp)[zoff + idx] = v;
                }
            }
        }
    }
}

// ---------------- V transpose: qkv[:, 2048+h*64+d] -> Vt (B,H,DK,S) ---------
__global__ void transpose_v(const bf16* __restrict__ qkv, bf16* __restrict__ vt) {
    __shared__ bf16 tile[32][33];
    int bh = blockIdx.z;
    int b = bh >> 4, h = bh & 15;
    int s0 = blockIdx.x * 32;
    int d0 = blockIdx.y * 32;
    int tx = threadIdx.x, ty = threadIdx.y;
    tile[ty][tx] = qkv[(size_t)(b * 1024 + s0 + ty) * QKVN + 2048 + h * 64 + d0 + tx];
    __syncthreads();
    vt[(size_t)(bh * 64 + d0 + ty) * 1024 + s0 + tx] = tile[tx][ty];
}

// ---------------- flash attention: 64 q-rows/block, LDS-staged K/V ----------
// Row-sum via ones-MFMA: osum = P @ 1 (C/D cols all equal row sum ->
// every lane holds its rows' sums; no sum shuffles, no final reduce).
__global__ __launch_bounds__(256) void attn_kernel(const bf16* __restrict__ qkv,
                                                   const bf16* __restrict__ Vt,
                                                   const int* __restrict__ mask,
                                                   bf16* __restrict__ out) {
    __shared__ bf16 Ks[2][4096];     // 16 KB
    __shared__ bf16 Vs[2][4096];     // 16 KB
    __shared__ bf16 pbuf[4][1024];   // 8 KB (per-wave P bounce, swizzled)
    __shared__ float msk[1024];      // 4 KB additive mask bias
    int tid = threadIdx.x;
    int lane = tid & 63, w = tid >> 6;
    int q = lane >> 4, r = lane & 15;
    int id = blockIdx.x;
    int qb = id & 15, h = (id >> 4) & 15, b = id >> 8;

    {
        int4 mi = reinterpret_cast<const int4*>(mask + b * 1024)[tid];
        msk[tid * 4 + 0] = mi.x ? 0.f : -1e9f;
        msk[tid * 4 + 1] = mi.y ? 0.f : -1e9f;
        msk[tid * 4 + 2] = mi.z ? 0.f : -1e9f;
        msk[tid * 4 + 3] = mi.w ? 0.f : -1e9f;
    }

    const bf16* qrow = qkv + (size_t)(b * 1024 + qb * 64 + w * 16 + r) * QKVN + h * 64 + q * 8;
    bf16x8 qf0 = *reinterpret_cast<const bf16x8*>(qrow);
    bf16x8 qf1 = *reinterpret_cast<const bf16x8*>(qrow + 32);

    int csw = (tid & 7) ^ ((tid >> 3) & 7);
    const bf16* kg0 = qkv + (size_t)(b * 1024 + (tid >> 3)) * QKVN + 1024 + h * 64 + csw * 8;
    const bf16* kg1 = kg0 + (size_t)32 * QKVN;
    const bf16* vg0 = Vt + (size_t)((b * 16 + h) * 64 + (tid >> 3)) * 1024 + csw * 8;
    const bf16* vg1 = vg0 + 32 * 1024;
    bf16* kld = &Ks[0][tid * 8];
    bf16* vld = &Vs[0][tid * 8];

    int co0 = (q ^ (r & 7)) * 8;
    bf16* pw = pbuf[w];
    bf16x8 ones;
    #pragma unroll
    for (int j = 0; j < 8; ++j) ones[j] = (bf16)1.0f;

    float m[4] = {-1e30f, -1e30f, -1e30f, -1e30f};
    f32x4 osum = {};
    f32x4 o[4] = {};

    gl_lds16(kg0, kld);
    gl_lds16(kg1, kld + 2048);
    gl_lds16(vg0, vld);
    gl_lds16(vg1, vld + 2048);

    for (int t = 0; t < 16; ++t) {
        __syncthreads();
        if (t < 15) {
            int ktn = (t + 1) * 64;
            int bo = ((t + 1) & 1) * 4096;
            gl_lds16(kg0 + (size_t)ktn * QKVN, kld + bo);
            gl_lds16(kg1 + (size_t)ktn * QKVN, kld + bo + 2048);
            gl_lds16(vg0 + ktn, vld + bo);
            gl_lds16(vg1 + ktn, vld + bo + 2048);
        }
        const bf16* Kb = Ks[t & 1];
        const bf16* Vb = Vs[t & 1];
        int kt = t * 64;

        f32x4 s[4];
        #pragma unroll
        for (int ks = 0; ks < 4; ++ks) {
            bf16x8 kf0 = *reinterpret_cast<const bf16x8*>(&Kb[(ks * 16 + r) * 64 + co0]);
            bf16x8 kf1 = *reinterpret_cast<const bf16x8*>(&Kb[(ks * 16 + r) * 64 + (co0 ^ 32)]);
            f32x4 a = {};
            a = __builtin_amdgcn_mfma_f32_16x16x32_bf16(qf0, kf0, a, 0, 0, 0);
            a = __builtin_amdgcn_mfma_f32_16x16x32_bf16(qf1, kf1, a, 0, 0, 0);
            float mb = msk[kt + ks * 16 + r];
            #pragma unroll
            for (int i = 0; i < 4; ++i) s[ks][i] = fmaf(a[i], 0.125f, mb);
        }
        float alpha[4];
        #pragma unroll
        for (int i = 0; i < 4; ++i) {
            float t2 = fmaxf(fmaxf(s[0][i], s[1][i]), fmaxf(s[2][i], s[3][i]));
            t2 = fmaxf(t2, __shfl_xor(t2, 1));
            t2 = fmaxf(t2, __shfl_xor(t2, 2));
            t2 = fmaxf(t2, __shfl_xor(t2, 4));
            t2 = fmaxf(t2, __shfl_xor(t2, 8));
            float mn = fmaxf(m[i], t2);
            alpha[i] = __expf(m[i] - mn);
            m[i] = mn;
        }
        #pragma unroll
        for (int i = 0; i < 4; ++i) {
            s[0][i] = __expf(s[0][i] - m[i]);
            s[1][i] = __expf(s[1][i] - m[i]);
            s[2][i] = __expf(s[2][i] - m[i]);
            s[3][i] = __expf(s[3][i] - m[i]);
        }
        #pragma unroll
        for (int i = 0; i < 4; ++i) {
            osum[i] *= alpha[i];
            o[0][i] *= alpha[i]; o[1][i] *= alpha[i];
            o[2][i] *= alpha[i]; o[3][i] *= alpha[i];
        }
        #pragma unroll
        for (int ks = 0; ks < 4; ++ks) {
            int kc = ks * 2 + (r >> 3);
            #pragma unroll
            for (int i = 0; i < 4; ++i) {
                int mr = q * 4 + i;
                pw[mr * 64 + ((kc ^ (mr & 7)) * 8) + (r & 7)] = (bf16)s[ks][i];
            }
        }
        #pragma unroll
        for (int ks2 = 0; ks2 < 2; ++ks2) {
            int vpo = (((ks2 * 4 + q) ^ (r & 7)) * 8);
            bf16x8 pf = *reinterpret_cast<const bf16x8*>(&pw[r * 64 + vpo]);
            #pragma unroll
            for (int nt = 0; nt < 4; ++nt) {
                bf16x8 vf = *reinterpret_cast<const bf16x8*>(&Vb[(nt * 16 + r) * 64 + vpo]);
                o[nt] = __builtin_amdgcn_mfma_f32_16x16x32_bf16(pf, vf, o[nt], 0, 0, 0);
            }
            osum = __builtin_amdgcn_mfma_f32_16x16x32_bf16(pf, ones, osum, 0, 0, 0);
        }
    }

    float inv[4];
    #pragma unroll
    for (int i = 0; i < 4; ++i) inv[i] = 1.0f / osum[i];
    #pragma unroll
    for (int nt = 0; nt < 4; ++nt)
        #pragma unroll
        for (int i = 0; i < 4; ++i)
            out[(size_t)(b * 1024 + qb * 64 + w * 16 + q * 4 + i) * DM + h * 64 + nt * 16 + r] =
                (bf16)(o[nt][i] * inv[i]);
}

// ---------------------------------------------------------------------------
extern "C" void kernel_launch(void* const* d_in, const int* in_sizes, int n_in,
                              void* d_out, int out_size, void* d_ws, size_t ws_size,
                              hipStream_t stream) {
    const float* x      = (const float*)d_in[0];
    const int*   mask   = (const int*)  d_in[1];
    const float* w_q    = (const float*)d_in[2];
    const float* w_k    = (const float*)d_in[3];
    const float* w_v    = (const float*)d_in[4];
    const float* w_o    = (const float*)d_in[5];
    const float* alpha1 = (const float*)d_in[6];
    const float* beta1  = (const float*)d_in[7];
    const float* alpha2 = (const float*)d_in[8];
    const float* beta2  = (const float*)d_in[9];
    const float* fc1_w  = (const float*)d_in[10];
    const float* fc1_b  = (const float*)d_in[11];
    const float* fc2_w  = (const float*)d_in[12];
    const float* fc2_b  = (const float*)d_in[13];
    float* out = (float*)d_out;

    char* ws = (char*)d_ws;
    const size_t MB = 1024 * 1024;
    bf16*  wqkv_b = (bf16*)(ws +  0 * MB);   // 6 MB  (dead after QKV gemm)
    bf16*  wo_b   = (bf16*)(ws +  6 * MB);   // 2 MB  (dead after o-proj)
    bf16*  f1w_b  = (bf16*)(ws +  8 * MB);   // 8 MB  (dead after fc1)
    bf16*  f2w_b  = (bf16*)(ws + 16 * MB);   // 8 MB
    bf16*  xn     = (bf16*)(ws + 24 * MB);   // 4 MB
    bf16*  qkvb   = (bf16*)(ws + 28 * MB);   // 12 MB (dead after attn)
    bf16*  vtb    = (bf16*)(ws + 40 * MB);   // 4 MB  (dead after attn)
    bf16*  attnb  = (bf16*)(ws + 44 * MB);   // 4 MB  (dead after o-proj)
    float* x2     = (float*)(ws + 48 * MB);  // 8 MB
    float* po     = (float*)(ws + 28 * MB);  // 16 MB o-proj partials (over qkv/vt)
    bf16*  hb     = (bf16*)(ws + 28 * MB);   // 16 MB fc1 out (over po)
    float* pf2    = (float*)(ws +  0 * MB);  // 16 MB fc2 partials (over dead weights)

    // 1) weights -> bf16 + ln1, one dispatch
    prep_kernel<<<14336, 256, 0, stream>>>(
        (const float4*)w_q, (const float4*)w_k, (const float4*)w_v, (const float4*)w_o,
        (const float4*)fc1_w, (const float4*)fc2_w,
        (bf16x4*)wqkv_b, (bf16x4*)wo_b, (bf16x4*)f1w_b, (bf16x4*)f2w_b,
        x, alpha1, beta1, xn);

    // 2) fused QKV projection (grid 768 = 3 blocks/CU)
    gemm64<0><<<dim3(QKVN / 64, NTOK / 128, 1), 256, 0, stream>>>(
        xn, wqkv_b, qkvb, nullptr, NTOK, QKVN, DM, DM);

    // 3) V -> (B,H,DK,S)
    transpose_v<<<dim3(32, 2, 32), dim3(32, 32), 0, stream>>>(qkvb, vtb);

    // 4) flash attention (512 blocks: 64 q-rows each)
    attn_kernel<<<512, 256, 0, stream>>>(qkvb, vtb, mask, attnb);

    // 5) o-proj split-K=2 partials (grid 512)
    gemm64<4><<<dim3(DM / 64, NTOK / 128, 2), 256, 0, stream>>>(
        attnb, wo_b, po, nullptr, NTOK, DM, DM, DM / 2);

    // 6) reduce + residual -> x2, fused ln2 -> xn
    reduce_ln_kernel<<<NTOK, 256, 0, stream>>>(po, x, alpha2, beta2, x2, xn);

    // 7) fc1 + bias + relu (grid 1024 = 4 blocks/CU)
    gemm64<1><<<dim3(DFC / 64, NTOK / 128, 1), 256, 0, stream>>>(
        xn, f1w_b, hb, fc1_b, NTOK, DFC, DM, DM);

    // 8) fc2 split-K=2 partials (grid 512)
    gemm64<4><<<dim3(DM / 64, NTOK / 128, 2), 256, 0, stream>>>(
        hb, f2w_b, pf2, nullptr, NTOK, DM, DFC, DFC / 2);

    // 9) reduce + bias + residual -> out
    reduce_out_kernel<<<2048, 256, 0, stream>>>(pf2, fc2_b, x2, out);
}

// Round 9
// 260.354 us; speedup vs baseline: 1.0555x; 1.0555x over previous
//
#include <hip/hip_runtime.h>
#include <hip/hip_bf16.h>

// ---------------------------------------------------------------------------
// EncoderBlock round 9:
//  - gemm128 (round-7 tile: 128x128, BK=64, dbuf 64KB, swizzled LDS) +
//    XCD-AWARE BLOCK SWIZZLE: linear id % 8 = XCD (dispatch heuristic);
//    remap so each XCD owns an N-stripe (B-slice <=1MB, L2-resident) and
//    sweeps M. Theory: FETCH 70MB vs 12MB compulsory = cross-XCD L2 refill;
//    staging is L2-miss-latency bound (occupancy/VALU both idle, r8).
//  - attn (round-8 ones-MFMA kernel) + XCD swizzle: 16 q-blocks of one
//    (b,h) on one XCD -> K/V 256KB L2-resident.
// MFMA layouts (verified): A[m=lane&15][k=(lane>>4)*8+j],
//   B[k=(lane>>4)*8+j][n=lane&15], C/D row=(lane>>4)*4+reg, col=lane&15.
// ---------------------------------------------------------------------------

typedef __bf16 bf16;
typedef __attribute__((ext_vector_type(8))) __bf16 bf16x8;
typedef __attribute__((ext_vector_type(4))) __bf16 bf16x4;
typedef __attribute__((ext_vector_type(4))) float f32x4;

#define NTOK 2048
#define DM   1024
#define DFC  4096
#define QKVN 3072

__device__ inline void gl_lds16(const void* g, void* l) {
    __builtin_amdgcn_global_load_lds((const __attribute__((address_space(1))) void*)g,
                                     (__attribute__((address_space(3))) void*)l, 16, 0, 0);
}

// ---------------- LayerNorm row helper (torch: std ddof=1, /(std+eps)) -----
__device__ inline void ln_row(float4 v, const float* alpha, const float* beta,
                              bf16* outrow, int t) {
    float s  = v.x + v.y + v.z + v.w;
    float ss = v.x * v.x + v.y * v.y + v.z * v.z + v.w * v.w;
    __shared__ float red[8];
    int lane = t & 63, wv = t >> 6;
    #pragma unroll
    for (int o = 32; o > 0; o >>= 1) {
        s  += __shfl_down(s, o);
        ss += __shfl_down(ss, o);
    }
    if (lane == 0) { red[wv] = s; red[4 + wv] = ss; }
    __syncthreads();
    float S  = red[0] + red[1] + red[2] + red[3];
    float SS = red[4] + red[5] + red[6] + red[7];
    float mean = S * (1.0f / 1024.0f);
    float var  = (SS - S * mean) * (1.0f / 1023.0f);
    var = var < 0.f ? 0.f : var;
    float inv = 1.0f / (sqrtf(var) + 1e-6f);
    float4 a4 = reinterpret_cast<const float4*>(alpha)[t];
    float4 b4 = reinterpret_cast<const float4*>(beta)[t];
    bf16x4 o4;
    o4[0] = (bf16)(a4.x * (v.x - mean) * inv + b4.x);
    o4[1] = (bf16)(a4.y * (v.y - mean) * inv + b4.y);
    o4[2] = (bf16)(a4.z * (v.z - mean) * inv + b4.z);
    o4[3] = (bf16)(a4.w * (v.w - mean) * inv + b4.w);
    reinterpret_cast<bf16x4*>(outrow)[t] = o4;
}

// ---------------- prep: all weights fp32->bf16 AND ln1, one dispatch --------
__global__ __launch_bounds__(256) void prep_kernel(
    const float4* __restrict__ wq, const float4* __restrict__ wk,
    const float4* __restrict__ wv, const float4* __restrict__ wo,
    const float4* __restrict__ f1, const float4* __restrict__ f2,
    bf16x4* __restrict__ oqkv, bf16x4* __restrict__ oo,
    bf16x4* __restrict__ of1, bf16x4* __restrict__ of2,
    const float* __restrict__ x, const float* __restrict__ alpha1,
    const float* __restrict__ beta1, bf16* __restrict__ xn) {
    int blk = blockIdx.x;
    int t = threadIdx.x;
    if (blk < 12288) {
        int i = blk * 256 + t;
        const int Q = 262144;                        // 1024*1024/4
        float4 v;
        bf16x4* dst;
        if (i < 3 * Q) {
            v = (i < Q) ? wq[i] : (i < 2 * Q) ? wk[i - Q] : wv[i - 2 * Q];
            dst = oqkv + i;
        } else if (i < 4 * Q) {
            v = wo[i - 3 * Q];
            dst = oo + (i - 3 * Q);
        } else if (i < 8 * Q) {
            v = f1[i - 4 * Q];
            dst = of1 + (i - 4 * Q);
        } else {
            v = f2[i - 8 * Q];
            dst = of2 + (i - 8 * Q);
        }
        bf16x4 o;
        o[0] = (bf16)v.x; o[1] = (bf16)v.y; o[2] = (bf16)v.z; o[3] = (bf16)v.w;
        *dst = o;
    } else {
        int row = blk - 12288;
        float4 v = reinterpret_cast<const float4*>(x + (size_t)row * DM)[t];
        ln_row(v, alpha1, beta1, xn + (size_t)row * DM, t);
    }
}

// ---- o-proj split-K reduce + residual -> x2, fused ln2 -> xn (block=row) ---
__global__ __launch_bounds__(256) void reduce_ln_kernel(const float* __restrict__ p,
                                                        const float* __restrict__ resid,
                                                        const float* __restrict__ alpha,
                                                        const float* __restrict__ beta,
                                                        float* __restrict__ x2,
                                                        bf16* __restrict__ xn) {
    int row = blockIdx.x, t = threadIdx.x;
    size_t i4 = (size_t)row * 256 + t;
    float4 a = reinterpret_cast<const float4*>(p)[i4];
    float4 b = reinterpret_cast<const float4*>(p)[i4 + 524288];
    float4 r = reinterpret_cast<const float4*>(resid)[i4];
    float4 v;
    v.x = a.x + b.x + r.x; v.y = a.y + b.y + r.y;
    v.z = a.z + b.z + r.z; v.w = a.w + b.w + r.w;
    reinterpret_cast<float4*>(x2)[i4] = v;
    ln_row(v, alpha, beta, xn + (size_t)row * DM, t);
}

// ---- fc2 split-K reduce + bias + residual -> d_out (fp32) ------------------
__global__ __launch_bounds__(256) void reduce_out_kernel(const float* __restrict__ p,
                                                         const float* __restrict__ bias,
                                                         const float* __restrict__ x2,
                                                         float* __restrict__ out) {
    size_t i4 = (size_t)blockIdx.x * 256 + threadIdx.x;
    float4 a = reinterpret_cast<const float4*>(p)[i4];
    float4 b = reinterpret_cast<const float4*>(p)[i4 + 524288];
    float4 r = reinterpret_cast<const float4*>(x2)[i4];
    float4 bi = reinterpret_cast<const float4*>(bias)[i4 & 255];
    float4 o;
    o.x = a.x + b.x + r.x + bi.x; o.y = a.y + b.y + r.y + bi.y;
    o.z = a.z + b.z + r.z + bi.z; o.w = a.w + b.w + r.w + bi.w;
    reinterpret_cast<float4*>(out)[i4] = o;
}

// ---------------- GEMM: 128x128 tile, BK=64, dbuf, swizzled LDS, XCD-swizzle-
// LDS: chunk c of row m at pos = c ^ (m&7); rows 128B -> 2-way banks (free).
// Block remap: lid = by0*gridX + bx0; xcd = lid&7 (dispatch heuristic);
// each XCD owns N-stripe of gridX/8 x-values (B-slice <=1MB L2-resident),
// sweeps all M within it. Bijective; perf-only (no correctness dependence).
// EPI: 0 = store bf16; 1 = relu(v+bias) bf16; 4 = fp32 partial at z*M*N
template <int EPI>
__global__ __launch_bounds__(256) void gemm128(const bf16* __restrict__ A,
                                               const bf16* __restrict__ Bt,
                                               void* __restrict__ outp,
                                               const float* __restrict__ bias,
                                               int M, int N, int K, int kslice) {
    __shared__ bf16 As[2][128 * 64];   // 32 KB
    __shared__ bf16 Bs[2][128 * 64];   // 32 KB
    int tid = threadIdx.x;
    int lane = tid & 63, wave = tid >> 6;
    int q = lane >> 4, r = lane & 15;
    int wm = wave >> 1, wn = wave & 1;

    // XCD-aware remap
    int lid = blockIdx.y * gridDim.x + blockIdx.x;
    int nxp = gridDim.x >> 3;          // x-blocks per XCD (gridX multiple of 8)
    int xcd = lid & 7;
    int loc = lid >> 3;
    int bx = xcd * nxp + (loc % nxp);
    int by = loc / nxp;

    int m0 = by * 128, n0 = bx * 128;
    int kbeg = blockIdx.z * kslice;
    int nit = kslice / 64;
    f32x4 acc[4][4] = {};

    int srow = tid >> 3;
    int csrc = (tid & 7) ^ (srow & 7);
    const bf16* agp = A  + (size_t)(m0 + srow) * K + kbeg + csrc * 8;
    const bf16* bgp = Bt + (size_t)(n0 + srow) * K + kbeg + csrc * 8;

    int rsw = (r & 7);
    int co0 = ((q ^ rsw) * 8);
    int co1 = co0 ^ 32;
    int aoff = (wm * 64 + r) * 64;
    int boff = (wn * 64 + r) * 64;

    auto stage = [&](int it, int b) {
        int k0 = it * 64;
        #pragma unroll
        for (int j = 0; j < 4; ++j) {
            gl_lds16(agp + (size_t)j * 32 * K + k0, &As[b][tid * 8 + j * 2048]);
            gl_lds16(bgp + (size_t)j * 32 * K + k0, &Bs[b][tid * 8 + j * 2048]);
        }
    };

    stage(0, 0);
    for (int it = 0; it < nit; ++it) {
        __syncthreads();                       // drains stage(it)
        if (it + 1 < nit) stage(it + 1, (it + 1) & 1);
        const bf16* Ab = &As[it & 1][aoff];
        const bf16* Bb = &Bs[it & 1][boff];
        #pragma unroll
        for (int half = 0; half < 2; ++half) {
            int co = half ? co1 : co0;
            bf16x8 af[4], bfv[4];
            #pragma unroll
            for (int t = 0; t < 4; ++t)
                af[t] = *reinterpret_cast<const bf16x8*>(Ab + t * 1024 + co);
            #pragma unroll
            for (int u = 0; u < 4; ++u)
                bfv[u] = *reinterpret_cast<const bf16x8*>(Bb + u * 1024 + co);
            #pragma unroll
            for (int t = 0; t < 4; ++t)
                #pragma unroll
                for (int u = 0; u < 4; ++u)
                    acc[t][u] = __builtin_amdgcn_mfma_f32_16x16x32_bf16(af[t], bfv[u], acc[t][u], 0, 0, 0);
        }
    }

    size_t zoff = (size_t)blockIdx.z * M * N;
    #pragma unroll
    for (int t = 0; t < 4; ++t) {
        #pragma unroll
        for (int u = 0; u < 4; ++u) {
            #pragma unroll
            for (int i = 0; i < 4; ++i) {
                int mm = m0 + wm * 64 + t * 16 + q * 4 + i;
                int nn = n0 + wn * 64 + u * 16 + r;
                size_t idx = (size_t)mm * N + nn;
                float v = acc[t][u][i];
                if (EPI == 0) {
                    ((bf16*)outp)[idx] = (bf16)v;
                } else if (EPI == 1) {
                    v += bias[nn];
                    ((bf16*)outp)[idx] = (bf16)(v > 0.f ? v : 0.f);
                } else {
                    ((float*)outp)[zoff + idx] = v;
                }
            }
        }
    }
}

// ---------------- V transpose: qkv[:, 2048+h*64+d] -> Vt (B,H,DK,S) ---------
__global__ void transpose_v(const bf16* __restrict__ qkv, bf16* __restrict__ vt) {
    __shared__ bf16 tile[32][33];
    int bh = blockIdx.z;
    int b = bh >> 4, h = bh & 15;
    int s0 = blockIdx.x * 32;
    int d0 = blockIdx.y * 32;
    int tx = threadIdx.x, ty = threadIdx.y;
    tile[ty][tx] = qkv[(size_t)(b * 1024 + s0 + ty) * QKVN + 2048 + h * 64 + d0 + tx];
    __syncthreads();
    vt[(size_t)(bh * 64 + d0 + ty) * 1024 + s0 + tx] = tile[tx][ty];
}

// ---------------- flash attention: 64 q-rows/block, LDS-staged K/V ----------
// XCD swizzle: all 16 q-blocks of one (b,h) on one XCD (K/V L2-resident).
// Row-sum via ones-MFMA (round 8, verified).
__global__ __launch_bounds__(256) void attn_kernel(const bf16* __restrict__ qkv,
                                                   const bf16* __restrict__ Vt,
                                                   const int* __restrict__ mask,
                                                   bf16* __restrict__ out) {
    __shared__ bf16 Ks[2][4096];     // 16 KB
    __shared__ bf16 Vs[2][4096];     // 16 KB
    __shared__ bf16 pbuf[4][1024];   // 8 KB
    __shared__ float msk[1024];      // 4 KB
    int tid = threadIdx.x;
    int lane = tid & 63, w = tid >> 6;
    int q = lane >> 4, r = lane & 15;

    // XCD remap: id%8 = xcd; per XCD 4 (b,h) pairs x 16 q-blocks
    int id = blockIdx.x;
    int xcd = id & 7, j = id >> 3;       // j in [0,64)
    int bh = xcd * 4 + (j >> 4);         // [0,32)
    int qb = j & 15;
    int b = bh >> 4, h = bh & 15;

    {
        int4 mi = reinterpret_cast<const int4*>(mask + b * 1024)[tid];
        msk[tid * 4 + 0] = mi.x ? 0.f : -1e9f;
        msk[tid * 4 + 1] = mi.y ? 0.f : -1e9f;
        msk[tid * 4 + 2] = mi.z ? 0.f : -1e9f;
        msk[tid * 4 + 3] = mi.w ? 0.f : -1e9f;
    }

    const bf16* qrow = qkv + (size_t)(b * 1024 + qb * 64 + w * 16 + r) * QKVN + h * 64 + q * 8;
    bf16x8 qf0 = *reinterpret_cast<const bf16x8*>(qrow);
    bf16x8 qf1 = *reinterpret_cast<const bf16x8*>(qrow + 32);

    int csw = (tid & 7) ^ ((tid >> 3) & 7);
    const bf16* kg0 = qkv + (size_t)(b * 1024 + (tid >> 3)) * QKVN + 1024 + h * 64 + csw * 8;
    const bf16* kg1 = kg0 + (size_t)32 * QKVN;
    const bf16* vg0 = Vt + (size_t)((b * 16 + h) * 64 + (tid >> 3)) * 1024 + csw * 8;
    const bf16* vg1 = vg0 + 32 * 1024;
    bf16* kld = &Ks[0][tid * 8];
    bf16* vld = &Vs[0][tid * 8];

    int co0 = (q ^ (r & 7)) * 8;
    bf16* pw = pbuf[w];
    bf16x8 ones;
    #pragma unroll
    for (int jj = 0; jj < 8; ++jj) ones[jj] = (bf16)1.0f;

    float m[4] = {-1e30f, -1e30f, -1e30f, -1e30f};
    f32x4 osum = {};
    f32x4 o[4] = {};

    gl_lds16(kg0, kld);
    gl_lds16(kg1, kld + 2048);
    gl_lds16(vg0, vld);
    gl_lds16(vg1, vld + 2048);

    for (int t = 0; t < 16; ++t) {
        __syncthreads();
        if (t < 15) {
            int ktn = (t + 1) * 64;
            int bo = ((t + 1) & 1) * 4096;
            gl_lds16(kg0 + (size_t)ktn * QKVN, kld + bo);
            gl_lds16(kg1 + (size_t)ktn * QKVN, kld + bo + 2048);
            gl_lds16(vg0 + ktn, vld + bo);
            gl_lds16(vg1 + ktn, vld + bo + 2048);
        }
        const bf16* Kb = Ks[t & 1];
        const bf16* Vb = Vs[t & 1];
        int kt = t * 64;

        f32x4 s[4];
        #pragma unroll
        for (int ks = 0; ks < 4; ++ks) {
            bf16x8 kf0 = *reinterpret_cast<const bf16x8*>(&Kb[(ks * 16 + r) * 64 + co0]);
            bf16x8 kf1 = *reinterpret_cast<const bf16x8*>(&Kb[(ks * 16 + r) * 64 + (co0 ^ 32)]);
            f32x4 a = {};
            a = __builtin_amdgcn_mfma_f32_16x16x32_bf16(qf0, kf0, a, 0, 0, 0);
            a = __builtin_amdgcn_mfma_f32_16x16x32_bf16(qf1, kf1, a, 0, 0, 0);
            float mb = msk[kt + ks * 16 + r];
            #pragma unroll
            for (int i = 0; i < 4; ++i) s[ks][i] = fmaf(a[i], 0.125f, mb);
        }
        float alpha[4];
        #pragma unroll
        for (int i = 0; i < 4; ++i) {
            float t2 = fmaxf(fmaxf(s[0][i], s[1][i]), fmaxf(s[2][i], s[3][i]));
            t2 = fmaxf(t2, __shfl_xor(t2, 1));
            t2 = fmaxf(t2, __shfl_xor(t2, 2));
            t2 = fmaxf(t2, __shfl_xor(t2, 4));
            t2 = fmaxf(t2, __shfl_xor(t2, 8));
            float mn = fmaxf(m[i], t2);
            alpha[i] = __expf(m[i] - mn);
            m[i] = mn;
        }
        #pragma unroll
        for (int i = 0; i < 4; ++i) {
            s[0][i] = __expf(s[0][i] - m[i]);
            s[1][i] = __expf(s[1][i] - m[i]);
            s[2][i] = __expf(s[2][i] - m[i]);
            s[3][i] = __expf(s[3][i] - m[i]);
        }
        #pragma unroll
        for (int i = 0; i < 4; ++i) {
            osum[i] *= alpha[i];
            o[0][i] *= alpha[i]; o[1][i] *= alpha[i];
            o[2][i] *= alpha[i]; o[3][i] *= alpha[i];
        }
        #pragma unroll
        for (int ks = 0; ks < 4; ++ks) {
            int kc = ks * 2 + (r >> 3);
            #pragma unroll
            for (int i = 0; i < 4; ++i) {
                int mr = q * 4 + i;
                pw[mr * 64 + ((kc ^ (mr & 7)) * 8) + (r & 7)] = (bf16)s[ks][i];
            }
        }
        #pragma unroll
        for (int ks2 = 0; ks2 < 2; ++ks2) {
            int vpo = (((ks2 * 4 + q) ^ (r & 7)) * 8);
            bf16x8 pf = *reinterpret_cast<const bf16x8*>(&pw[r * 64 + vpo]);
            #pragma unroll
            for (int nt = 0; nt < 4; ++nt) {
                bf16x8 vf = *reinterpret_cast<const bf16x8*>(&Vb[(nt * 16 + r) * 64 + vpo]);
                o[nt] = __builtin_amdgcn_mfma_f32_16x16x32_bf16(pf, vf, o[nt], 0, 0, 0);
            }
            osum = __builtin_amdgcn_mfma_f32_16x16x32_bf16(pf, ones, osum, 0, 0, 0);
        }
    }

    float inv[4];
    #pragma unroll
    for (int i = 0; i < 4; ++i) inv[i] = 1.0f / osum[i];
    #pragma unroll
    for (int nt = 0; nt < 4; ++nt)
        #pragma unroll
        for (int i = 0; i < 4; ++i)
            out[(size_t)(b * 1024 + qb * 64 + w * 16 + q * 4 + i) * DM + h * 64 + nt * 16 + r] =
                (bf16)(o[nt][i] * inv[i]);
}

// ---------------------------------------------------------------------------
extern "C" void kernel_launch(void* const* d_in, const int* in_sizes, int n_in,
                              void* d_out, int out_size, void* d_ws, size_t ws_size,
                              hipStream_t stream) {
    const float* x      = (const float*)d_in[0];
    const int*   mask   = (const int*)  d_in[1];
    const float* w_q    = (const float*)d_in[2];
    const float* w_k    = (const float*)d_in[3];
    const float* w_v    = (const float*)d_in[4];
    const float* w_o    = (const float*)d_in[5];
    const float* alpha1 = (const float*)d_in[6];
    const float* beta1  = (const float*)d_in[7];
    const float* alpha2 = (const float*)d_in[8];
    const float* beta2  = (const float*)d_in[9];
    const float* fc1_w  = (const float*)d_in[10];
    const float* fc1_b  = (const float*)d_in[11];
    const float* fc2_w  = (const float*)d_in[12];
    const float* fc2_b  = (const float*)d_in[13];
    float* out = (float*)d_out;

    char* ws = (char*)d_ws;
    const size_t MB = 1024 * 1024;
    bf16*  wqkv_b = (bf16*)(ws +  0 * MB);   // 6 MB  (dead after QKV gemm)
    bf16*  wo_b   = (bf16*)(ws +  6 * MB);   // 2 MB  (dead after o-proj)
    bf16*  f1w_b  = (bf16*)(ws +  8 * MB);   // 8 MB  (dead after fc1)
    bf16*  f2w_b  = (bf16*)(ws + 16 * MB);   // 8 MB
    bf16*  xn     = (bf16*)(ws + 24 * MB);   // 4 MB
    bf16*  qkvb   = (bf16*)(ws + 28 * MB);   // 12 MB (dead after attn)
    bf16*  vtb    = (bf16*)(ws + 40 * MB);   // 4 MB  (dead after attn)
    bf16*  attnb  = (bf16*)(ws + 44 * MB);   // 4 MB  (dead after o-proj)
    float* x2     = (float*)(ws + 48 * MB);  // 8 MB
    float* po     = (float*)(ws + 28 * MB);  // 16 MB o-proj partials (over qkv/vt)
    bf16*  hb     = (bf16*)(ws + 28 * MB);   // 16 MB fc1 out (over po)
    float* pf2    = (float*)(ws +  0 * MB);  // 16 MB fc2 partials (over dead weights)

    // 1) weights -> bf16 + ln1, one dispatch
    prep_kernel<<<14336, 256, 0, stream>>>(
        (const float4*)w_q, (const float4*)w_k, (const float4*)w_v, (const float4*)w_o,
        (const float4*)fc1_w, (const float4*)fc2_w,
        (bf16x4*)wqkv_b, (bf16x4*)wo_b, (bf16x4*)f1w_b, (bf16x4*)f2w_b,
        x, alpha1, beta1, xn);

    // 2) fused QKV projection (grid 24x16)
    gemm128<0><<<dim3(QKVN / 128, NTOK / 128, 1), 256, 0, stream>>>(
        xn, wqkv_b, qkvb, nullptr, NTOK, QKVN, DM, DM);

    // 3) V -> (B,H,DK,S)
    transpose_v<<<dim3(32, 2, 32), dim3(32, 32), 0, stream>>>(qkvb, vtb);

    // 4) flash attention (512 blocks, XCD-swizzled)
    attn_kernel<<<512, 256, 0, stream>>>(qkvb, vtb, mask, attnb);

    // 5) o-proj split-K=2 partials (grid 8x16x2)
    gemm128<4><<<dim3(DM / 128, NTOK / 128, 2), 256, 0, stream>>>(
        attnb, wo_b, po, nullptr, NTOK, DM, DM, DM / 2);

    // 6) reduce + residual -> x2, fused ln2 -> xn
    reduce_ln_kernel<<<NTOK, 256, 0, stream>>>(po, x, alpha2, beta2, x2, xn);

    // 7) fc1 + bias + relu (grid 32x16)
    gemm128<1><<<dim3(DFC / 128, NTOK / 128, 1), 256, 0, stream>>>(
        xn, f1w_b, hb, fc1_b, NTOK, DFC, DM, DM);

    // 8) fc2 split-K=2 partials (grid 8x16x2)
    gemm128<4><<<dim3(DM / 128, NTOK / 128, 2), 256, 0, stream>>>(
        hb, f2w_b, pf2, nullptr, NTOK, DM, DFC, DFC / 2);

    // 9) reduce + bias + residual -> out
    reduce_out_kernel<<<2048, 256, 0, stream>>>(pf2, fc2_b, x2, out);
}